// Round 2
// baseline (762.716 us; speedup 1.0000x reference)
//
#include <hip/hip_runtime.h>

#define NUM_TAGS 128
#define NUM_FEATS 500000
#define BB 64
#define TT 512
#define FF 8

#define SWT_BYTES 256000000ull            // 500000*128*4

typedef float f2 __attribute__((ext_vector_type(2)));

// Raw workgroup barrier that does NOT drain vmcnt: only LDS (lgkmcnt) is
// waited, so prefetched global gather loads stay in flight across steps.
// sched_barrier(0) on both sides pins LDS ops to their side of the barrier.
__device__ __forceinline__ void barrier_lds() {
  __builtin_amdgcn_sched_barrier(0);
  asm volatile("s_waitcnt lgkmcnt(0)" ::: "memory");
  __builtin_amdgcn_s_barrier();
  __builtin_amdgcn_sched_barrier(0);
}

// T1: transpose state_weights [128][500000] -> swT [500000][128]. (unchanged, proven)
__global__ __launch_bounds__(256) void transpose_kernel(
    const float* __restrict__ sw, float* __restrict__ swT) {
  __shared__ float tile[32][129];
  const int f0 = blockIdx.x * 32;
  const int t = threadIdx.x;
  const int fi = t & 31, kb = t >> 5;          // kb 0..7
#pragma unroll
  for (int it = 0; it < 16; ++it) {
    int k = kb + it * 8;
    tile[fi][k] = sw[(size_t)k * NUM_FEATS + f0 + fi];  // 128B coalesced
  }
  __syncthreads();
  const int k2 = t & 127, fo = t >> 7;         // fo 0..1
#pragma unroll
  for (int it = 0; it < 16; ++it) {
    int f2i = fo + it * 2;
    swT[(size_t)(f0 + f2i) * NUM_TAGS + k2] = tile[f2i][k2];  // 512B coalesced
  }
}

// Load the 8 emission-feature values for step t into a named register buffer.
// Feature indices come from LDS (broadcast reads), so the global loads have no
// chained latency and can be issued 4 steps ahead.
template <bool TR>
__device__ __forceinline__ void loadf(float (&buf)[8], const int* sfeats, int t,
                                      const float* __restrict__ swx, int j) {
  const int4 fa = ((const int4*)sfeats)[t * 2];
  const int4 fb = ((const int4*)sfeats)[t * 2 + 1];
  if (TR) {
    buf[0] = swx[(size_t)fa.x * NUM_TAGS + j];
    buf[1] = swx[(size_t)fa.y * NUM_TAGS + j];
    buf[2] = swx[(size_t)fa.z * NUM_TAGS + j];
    buf[3] = swx[(size_t)fa.w * NUM_TAGS + j];
    buf[4] = swx[(size_t)fb.x * NUM_TAGS + j];
    buf[5] = swx[(size_t)fb.y * NUM_TAGS + j];
    buf[6] = swx[(size_t)fb.z * NUM_TAGS + j];
    buf[7] = swx[(size_t)fb.w * NUM_TAGS + j];
  } else {
    const float* row = swx + (size_t)j * NUM_FEATS;
    buf[0] = row[fa.x]; buf[1] = row[fa.y]; buf[2] = row[fa.z]; buf[3] = row[fa.w];
    buf[4] = row[fb.x]; buf[5] = row[fb.y]; buf[6] = row[fb.z]; buf[7] = row[fb.w];
  }
}

// One forward step: consume buf (emissions for step t), immediately re-issue its
// loads for step t+4, then alpha_dst[j] = (alpha_src . expT[:,j]) * exp(em) * 2^-7.
// Single raw barrier per step (double-buffered alpha; reads precede writes).
template <bool TR>
__device__ __forceinline__ void stepf(float (&buf)[8], const int* sfeats,
                                      const int* stags, int t,
                                      const float* __restrict__ swx, int j,
                                      const float* alf_src, float* alf_dst,
                                      const f2 (&eT2)[64], float& gold_em) {
  float s = ((buf[0] + buf[1]) + (buf[2] + buf[3])) +
            ((buf[4] + buf[5]) + (buf[6] + buf[7]));
  int tn = t + 4; if (tn > TT - 1) tn = TT - 1;       // clamp (redundant reload ok)
  loadf<TR>(buf, sfeats, tn, swx, j);                 // prefetch 4 steps ahead
  float ev = __expf(s);
  if (j == stags[t]) gold_em += s;                    // gold emission, log-space
  f2 acc0 = {0.f, 0.f}, acc1 = {0.f, 0.f}, acc2 = {0.f, 0.f}, acc3 = {0.f, 0.f};
  const float4* a4 = (const float4*)alf_src;          // wave-uniform: LDS broadcast
#pragma unroll
  for (int i = 0; i < 16; ++i) {
    float4 a = a4[2 * i];
    float4 b = a4[2 * i + 1];
    acc0 += (f2){a.x, a.y} * eT2[4 * i + 0];
    acc1 += (f2){a.z, a.w} * eT2[4 * i + 1];
    acc2 += (f2){b.x, b.y} * eT2[4 * i + 2];
    acc3 += (f2){b.z, b.w} * eT2[4 * i + 3];
  }
  f2 sA = acc0 + acc2, sB = acc1 + acc3;
  float dot = (sA.x + sA.y) + (sB.x + sB.y);
  alf_dst[j] = dot * ev * 0.0078125f;                 // * 2^-7 rescale
  barrier_lds();
}

// K2': fused gather + prob-space forward. 128 threads (2 waves), thread j owns
// output column j; expT column in 64 f2 VGPRs; 1 raw barrier/step; 0 bank conflicts.
template <bool TR>
__global__ __launch_bounds__(128) void fwd_fused_kernel(
    const int* __restrict__ feats, const int* __restrict__ tags,
    const float* __restrict__ swx, const float* __restrict__ trans,
    const float* __restrict__ startT, const float* __restrict__ endT,
    float* __restrict__ out) {
  const int b = blockIdx.x;
  const int j = threadIdx.x;  // 0..127

  __shared__ __align__(16) float alf[2][NUM_TAGS];    // double-buffered alpha
  __shared__ __align__(16) int sfeats[TT * FF];       // 16 KB
  __shared__ __align__(16) int stags[TT];             // 2 KB
  __shared__ float sred[4];

  // stage feats + tags into LDS (coalesced int4)
  const int4* gF = (const int4*)(feats + (size_t)b * TT * FF);
  int4* sF4 = (int4*)sfeats;
#pragma unroll
  for (int p = 0; p < 8; ++p) sF4[j + 128 * p] = gF[j + 128 * p];
  ((int4*)stags)[j] = ((const int4*)(tags + (size_t)b * TT))[j];

  // expT column j into registers (coalesced loads over rows)
  f2 eT2[64];
#pragma unroll
  for (int m = 0; m < 64; ++m) {
    eT2[m].x = __expf(trans[(2 * m) * NUM_TAGS + j]);
    eT2[m].y = __expf(trans[(2 * m + 1) * NUM_TAGS + j]);
  }
  barrier_lds();

  float bA[8], bB[8], bC[8], bD[8];
  float gold_em = 0.f;

  loadf<TR>(bA, sfeats, 0, swx, j);
  loadf<TR>(bB, sfeats, 1, swx, j);
  loadf<TR>(bC, sfeats, 2, swx, j);
  loadf<TR>(bD, sfeats, 3, swx, j);

  // t = 0: init alpha
  {
    float s = ((bA[0] + bA[1]) + (bA[2] + bA[3])) +
              ((bA[4] + bA[5]) + (bA[6] + bA[7]));
    loadf<TR>(bA, sfeats, 4, swx, j);
    float ev = __expf(s);
    if (j == stags[0]) gold_em += s;
    alf[0][j] = __expf(startT[j]) * ev;
    barrier_lds();
  }

  int cur = 0;
  // steps 1..508 in groups of 4 (buffers B,C,D,A), then tail 509..511
  for (int t = 1; t + 6 < TT; t += 4) {
    stepf<TR>(bB, sfeats, stags, t + 0, swx, j, alf[cur], alf[cur ^ 1], eT2, gold_em); cur ^= 1;
    stepf<TR>(bC, sfeats, stags, t + 1, swx, j, alf[cur], alf[cur ^ 1], eT2, gold_em); cur ^= 1;
    stepf<TR>(bD, sfeats, stags, t + 2, swx, j, alf[cur], alf[cur ^ 1], eT2, gold_em); cur ^= 1;
    stepf<TR>(bA, sfeats, stags, t + 3, swx, j, alf[cur], alf[cur ^ 1], eT2, gold_em); cur ^= 1;
  }
  stepf<TR>(bB, sfeats, stags, 509, swx, j, alf[cur], alf[cur ^ 1], eT2, gold_em); cur ^= 1;
  stepf<TR>(bC, sfeats, stags, 510, swx, j, alf[cur], alf[cur ^ 1], eT2, gold_em); cur ^= 1;
  stepf<TR>(bD, sfeats, stags, 511, swx, j, alf[cur], alf[cur ^ 1], eT2, gold_em); cur ^= 1;

  // logZ: reduce alf[cur][j] * exp(end[j]) over 128 threads
  float val = alf[cur][j] * __expf(endT[j]);
#pragma unroll
  for (int off = 32; off > 0; off >>= 1) val += __shfl_down(val, off, 64);
  if ((j & 63) == 0) sred[j >> 6] = val;

  // gold: transition terms (+ start/end), plus accumulated emissions
  float g = gold_em;
#pragma unroll
  for (int p = 0; p < 4; ++p) {
    int t = j + 128 * p;
    int tg = stags[t];
    if (t < TT - 1) g += trans[tg * NUM_TAGS + stags[t + 1]];
  }
  if (j == 0) g += startT[stags[0]] + endT[stags[TT - 1]];
#pragma unroll
  for (int off = 32; off > 0; off >>= 1) g += __shfl_down(g, off, 64);
  if ((j & 63) == 0) sred[2 + (j >> 6)] = g;
  barrier_lds();

  if (j == 0) {
    float logz = __logf(sred[0] + sred[1]) + 511.0f * 7.0f * 0.69314718055994531f;
    out[b] = logz - (sred[2] + sred[3]);
  }
}

extern "C" void kernel_launch(void* const* d_in, const int* in_sizes, int n_in,
                              void* d_out, int out_size, void* d_ws, size_t ws_size,
                              hipStream_t stream) {
  const int* feats = (const int*)d_in[0];
  const int* tags = (const int*)d_in[1];
  const float* sw = (const float*)d_in[2];
  const float* trans = (const float*)d_in[3];
  const float* startT = (const float*)d_in[4];
  const float* endT = (const float*)d_in[5];
  float* out = (float*)d_out;

  if (ws_size >= SWT_BYTES) {
    float* swT = (float*)d_ws;
    transpose_kernel<<<NUM_FEATS / 32, 256, 0, stream>>>(sw, swT);
    fwd_fused_kernel<true><<<BB, 128, 0, stream>>>(feats, tags, swT, trans, startT, endT, out);
  } else {
    fwd_fused_kernel<false><<<BB, 128, 0, stream>>>(feats, tags, sw, trans, startT, endT, out);
  }
}

// Round 4
// 565.366 us; speedup vs baseline: 1.3491x; 1.3491x over previous
//
#include <hip/hip_runtime.h>

#define NUM_TAGS 128
#define NUM_FEATS 500000
#define BB 64
#define TT 512
#define FF 8

#define SWT_BYTES 256000000ull            // 500000*128*4
#define EM_BYTES  16777216ull             // 64*512*128*4
#define NEED_FULL (SWT_BYTES + EM_BYTES)

typedef float f2 __attribute__((ext_vector_type(2)));

// Padded alpha index: quarter g>>5 stored at stride 36 floats (144 B, 16B-aligned)
// -> the 4 per-quarter broadcast groups of a ds_read_b128 hit disjoint banks.
#define AP(j) ((((j) >> 5) * 36) + ((j) & 31))

// Raw workgroup barrier: wait LDS ops only (no vmcnt drain), so the 4-deep
// ev prefetch stays in flight across steps. sched_barrier(0) AFTER s_barrier
// keeps next-step ds_reads from hoisting above the barrier (m152-class race).
__device__ __forceinline__ void barrier_lds() {
  asm volatile("s_waitcnt lgkmcnt(0)" ::: "memory");
  __builtin_amdgcn_s_barrier();
  __builtin_amdgcn_sched_barrier(0);
}

// T1: transpose state_weights [128][500000] -> swT [500000][128]. (round-0, proven)
__global__ __launch_bounds__(256) void transpose_kernel(
    const float* __restrict__ sw, float* __restrict__ swT) {
  __shared__ float tile[32][129];
  const int f0 = blockIdx.x * 32;
  const int t = threadIdx.x;
  const int fi = t & 31, kb = t >> 5;          // kb 0..7
#pragma unroll
  for (int it = 0; it < 16; ++it) {
    int k = kb + it * 8;
    tile[fi][k] = sw[(size_t)k * NUM_FEATS + f0 + fi];  // 128B coalesced
  }
  __syncthreads();
  const int k2 = t & 127, fo = t >> 7;         // fo 0..1
#pragma unroll
  for (int it = 0; it < 16; ++it) {
    int f2i = fo + it * 2;
    swT[(size_t)(f0 + f2i) * NUM_TAGS + k2] = tile[f2i][k2];  // 512B coalesced
  }
}

// K1a: emissions from transposed table; exp() folded. (round-0, proven)
__global__ __launch_bounds__(128) void gather_t_kernel(
    const int* __restrict__ feats, const float* __restrict__ swT,
    float* __restrict__ em_exp) {
  const int token = blockIdx.x;
  const int k = threadIdx.x;
  const int* f = feats + token * FF;
  float s = 0.f;
#pragma unroll
  for (int i = 0; i < FF; ++i) s += swT[(size_t)f[i] * NUM_TAGS + k];
  em_exp[(size_t)token * NUM_TAGS + k] = __expf(s);
}

// K1b fallback: direct strided gather. (round-0, proven)
__global__ __launch_bounds__(128) void gather_f_kernel(
    const int* __restrict__ feats, const float* __restrict__ sw,
    float* __restrict__ em_exp) {
  const int token = blockIdx.x;
  const int k = threadIdx.x;
  const int* f = feats + token * FF;
  const float* row = sw + (size_t)k * NUM_FEATS;
  float s = 0.f;
#pragma unroll
  for (int i = 0; i < FF; ++i) s += row[f[i]];
  em_exp[(size_t)token * NUM_TAGS + k] = __expf(s);
}

// One forward step. tid = j*4+q: lanes 4j..4j+3 hold the 4 quarters of column j,
// so the partial reduce is 2 shfl_xor in-wave; ONE lgkm-only barrier per step.
__device__ __forceinline__ void stepv(float& evreg, int t,
                                      const float* __restrict__ embx,
                                      int j, int q, const float* alf_src,
                                      float* alf_dst, const f2 (&eTv)[16]) {
  float ev = evreg;
  int tp = t + 4; if (tp > TT - 1) tp = TT - 1;        // clamp (redundant reload ok)
  evreg = embx[tp * NUM_TAGS + j];                     // prefetch 4 steps ahead
  const float4* a4 = (const float4*)(alf_src + q * 36);
  f2 acc0 = {0.f, 0.f}, acc1 = {0.f, 0.f};
#pragma unroll
  for (int i = 0; i < 8; ++i) {
    float4 a = a4[i];                                  // conflict-free (padded quarters)
    acc0 += (f2){a.x, a.y} * eTv[2 * i];
    acc1 += (f2){a.z, a.w} * eTv[2 * i + 1];
  }
  float r = (acc0.x + acc0.y) + (acc1.x + acc1.y);
  r += __shfl_xor(r, 1, 64);
  r += __shfl_xor(r, 2, 64);
  if (q == 0) alf_dst[AP(j)] = r * ev * 0.0078125f;    // * 2^-7 rescale
  barrier_lds();
}

// K2: prob-space forward. 512 threads, j=tid>>2 owns output column, q=tid&3 the
// sum quarter (32 FMAs). eTv: 32 VGPRs/thread. 1 barrier/step, 0 bank conflicts.
__global__ __launch_bounds__(512, 1) void fwd_kernel(
    const float* __restrict__ em_exp, const int* __restrict__ tags,
    const float* __restrict__ trans, const float* __restrict__ startT,
    const float* __restrict__ endT, float* __restrict__ out) {
  const int b = blockIdx.x;
  const int tid = threadIdx.x;
  const int j = tid >> 2, q = tid & 3;

  __shared__ __align__(16) float alf[2][144];          // double-buffered, padded
  __shared__ float sred[16];

  f2 eTv[16];                                          // expT rows 32q..32q+31, col j
#pragma unroll
  for (int i = 0; i < 16; ++i) {
    eTv[i].x = __expf(trans[(32 * q + 2 * i) * NUM_TAGS + j]);
    eTv[i].y = __expf(trans[(32 * q + 2 * i + 1) * NUM_TAGS + j]);
  }

  const float* embx = em_exp + (size_t)b * TT * NUM_TAGS;

  if (q == 0) alf[0][AP(j)] = __expf(startT[j]) * embx[j];

  float evA = embx[1 * NUM_TAGS + j], evB = embx[2 * NUM_TAGS + j],
        evC = embx[3 * NUM_TAGS + j], evD = embx[4 * NUM_TAGS + j];
  __syncthreads();

  int cur = 0;
  for (int t = 1; t + 3 < TT; t += 4) {                // t = 1..505, steps t..t+3
    stepv(evA, t + 0, embx, j, q, alf[cur], alf[cur ^ 1], eTv); cur ^= 1;
    stepv(evB, t + 1, embx, j, q, alf[cur], alf[cur ^ 1], eTv); cur ^= 1;
    stepv(evC, t + 2, embx, j, q, alf[cur], alf[cur ^ 1], eTv); cur ^= 1;
    stepv(evD, t + 3, embx, j, q, alf[cur], alf[cur ^ 1], eTv); cur ^= 1;
  }
  stepv(evA, 509, embx, j, q, alf[cur], alf[cur ^ 1], eTv); cur ^= 1;
  stepv(evB, 510, embx, j, q, alf[cur], alf[cur ^ 1], eTv); cur ^= 1;
  stepv(evC, 511, embx, j, q, alf[cur], alf[cur ^ 1], eTv); cur ^= 1;

  // logZ: threads 0..127 (waves 0-1), reduce alpha * exp(end)
  if (tid < 128) {
    float val = alf[cur][AP(tid)] * __expf(endT[tid]);
#pragma unroll
    for (int off = 32; off > 0; off >>= 1) val += __shfl_down(val, off, 64);
    if ((tid & 63) == 0) sred[tid >> 6] = val;
  }

  // gold: thread tid handles t = tid
  const int* tb = tags + b * TT;
  const int t = tid;
  const int tg = tb[t];
  float g = __logf(embx[t * NUM_TAGS + tg]);
  if (t < TT - 1) g += trans[tg * NUM_TAGS + tb[t + 1]];
  if (t == 0) g += startT[tb[0]] + endT[tb[TT - 1]];
#pragma unroll
  for (int off = 32; off > 0; off >>= 1) g += __shfl_down(g, off, 64);
  if ((tid & 63) == 0) sred[8 + (tid >> 6)] = g;
  __syncthreads();

  if (tid == 0) {
    float logz = __logf(sred[0] + sred[1]) + 511.0f * 7.0f * 0.69314718055994531f;
    float gs = 0.f;
#pragma unroll
    for (int i = 0; i < 8; ++i) gs += sred[8 + i];
    out[b] = logz - gs;
  }
}

extern "C" void kernel_launch(void* const* d_in, const int* in_sizes, int n_in,
                              void* d_out, int out_size, void* d_ws, size_t ws_size,
                              hipStream_t stream) {
  const int* feats = (const int*)d_in[0];
  const int* tags = (const int*)d_in[1];
  const float* sw = (const float*)d_in[2];
  const float* trans = (const float*)d_in[3];
  const float* startT = (const float*)d_in[4];
  const float* endT = (const float*)d_in[5];
  float* out = (float*)d_out;

  if (ws_size >= NEED_FULL) {
    float* swT = (float*)d_ws;
    float* em_exp = (float*)((char*)d_ws + SWT_BYTES);
    transpose_kernel<<<NUM_FEATS / 32, 256, 0, stream>>>(sw, swT);
    gather_t_kernel<<<BB * TT, 128, 0, stream>>>(feats, swT, em_exp);
    fwd_kernel<<<BB, 512, 0, stream>>>(em_exp, tags, trans, startT, endT, out);
  } else {
    float* em_exp = (float*)d_ws;
    gather_f_kernel<<<BB * TT, 128, 0, stream>>>(feats, sw, em_exp);
    fwd_kernel<<<BB, 512, 0, stream>>>(em_exp, tags, trans, startT, endT, out);
  }
}

// Round 5
// 540.580 us; speedup vs baseline: 1.4109x; 1.0459x over previous
//
#include <hip/hip_runtime.h>

#define NUM_TAGS 128
#define NUM_FEATS 500000
#define BB 64
#define TT 512
#define FF 8

#define SWT_BYTES 256000000ull            // 500000*128*4
#define EM_BYTES  16777216ull             // 64*512*128*4
#define NEED_FULL (SWT_BYTES + EM_BYTES)

typedef float f2 __attribute__((ext_vector_type(2)));

// Padded alpha index: quarter g>>5 stored at stride 36 floats (144 B, 16B-aligned)
// -> the 4 per-quarter broadcast groups of a ds_read_b128 hit disjoint banks.
#define AP(j) ((((j) >> 5) * 36) + ((j) & 31))

// Raw workgroup barrier: wait LDS ops only (no vmcnt drain), so the 4-deep
// ev prefetch stays in flight across steps. sched_barrier(0) AFTER s_barrier
// keeps next-step ds_reads from hoisting above the barrier (m152-class race).
__device__ __forceinline__ void barrier_lds() {
  asm volatile("s_waitcnt lgkmcnt(0)" ::: "memory");
  __builtin_amdgcn_s_barrier();
  __builtin_amdgcn_sched_barrier(0);
}

// Quad butterfly sum via DPP (VALU pipe, ~8 cy) — replaces 2x ds-pipe shfl_xor
// (~240 cy). Lanes 4j..4j+3 all end with the full 4-lane sum.
__device__ __forceinline__ float quad_sum_dpp(float r) {
  int t1 = __builtin_amdgcn_mov_dpp(__builtin_bit_cast(int, r), 0xB1, 0xF, 0xF, true);
  r += __builtin_bit_cast(float, t1);                  // quad_perm [1,0,3,2]: xor 1
  int t2 = __builtin_amdgcn_mov_dpp(__builtin_bit_cast(int, r), 0x4E, 0xF, 0xF, true);
  r += __builtin_bit_cast(float, t2);                  // quad_perm [2,3,0,1]: xor 2
  return r;
}

// T1: transpose state_weights [128][500000] -> swT [500000][128]. (round-0, proven)
__global__ __launch_bounds__(256) void transpose_kernel(
    const float* __restrict__ sw, float* __restrict__ swT) {
  __shared__ float tile[32][129];
  const int f0 = blockIdx.x * 32;
  const int t = threadIdx.x;
  const int fi = t & 31, kb = t >> 5;          // kb 0..7
#pragma unroll
  for (int it = 0; it < 16; ++it) {
    int k = kb + it * 8;
    tile[fi][k] = sw[(size_t)k * NUM_FEATS + f0 + fi];  // 128B coalesced
  }
  __syncthreads();
  const int k2 = t & 127, fo = t >> 7;         // fo 0..1
#pragma unroll
  for (int it = 0; it < 16; ++it) {
    int f2i = fo + it * 2;
    swT[(size_t)(f0 + f2i) * NUM_TAGS + k2] = tile[f2i][k2];  // 512B coalesced
  }
}

// K1a: emissions from transposed table; exp() folded. (round-0, proven)
__global__ __launch_bounds__(128) void gather_t_kernel(
    const int* __restrict__ feats, const float* __restrict__ swT,
    float* __restrict__ em_exp) {
  const int token = blockIdx.x;
  const int k = threadIdx.x;
  const int* f = feats + token * FF;
  float s = 0.f;
#pragma unroll
  for (int i = 0; i < FF; ++i) s += swT[(size_t)f[i] * NUM_TAGS + k];
  em_exp[(size_t)token * NUM_TAGS + k] = __expf(s);
}

// K1b fallback: direct strided gather. (round-0, proven)
__global__ __launch_bounds__(128) void gather_f_kernel(
    const int* __restrict__ feats, const float* __restrict__ sw,
    float* __restrict__ em_exp) {
  const int token = blockIdx.x;
  const int k = threadIdx.x;
  const int* f = feats + token * FF;
  const float* row = sw + (size_t)k * NUM_FEATS;
  float s = 0.f;
#pragma unroll
  for (int i = 0; i < FF; ++i) s += row[f[i]];
  em_exp[(size_t)token * NUM_TAGS + k] = __expf(s);
}

// One forward step. tid = j*4+q: lanes 4j..4j+3 hold the 4 quarters of column j;
// partial reduce is a DPP quad butterfly (VALU); ONE lgkm-only barrier per step.
__device__ __forceinline__ void stepv(float& evreg, int t,
                                      const float* __restrict__ embx,
                                      int j, int q, const float* alf_src,
                                      float* alf_dst, const f2 (&eTv)[16]) {
  float ev = evreg;
  int tp = t + 4; if (tp > TT - 1) tp = TT - 1;        // clamp (redundant reload ok)
  evreg = embx[tp * NUM_TAGS + j];                     // prefetch 4 steps ahead
  const float4* a4 = (const float4*)(alf_src + q * 36);
  f2 acc0 = {0.f, 0.f}, acc1 = {0.f, 0.f};
#pragma unroll
  for (int i = 0; i < 8; ++i) {
    float4 a = a4[i];                                  // conflict-free (padded quarters)
    acc0 += (f2){a.x, a.y} * eTv[2 * i];
    acc1 += (f2){a.z, a.w} * eTv[2 * i + 1];
  }
  float r = (acc0.x + acc0.y) + (acc1.x + acc1.y);
  r = quad_sum_dpp(r);
  if (q == 0) alf_dst[AP(j)] = r * ev * 0.0078125f;    // * 2^-7 rescale
  barrier_lds();
}

// K2: prob-space forward. 512 threads, j=tid>>2 owns output column, q=tid&3 the
// sum quarter (32 FMAs). eTv: 32 VGPRs/thread. 1 barrier/step, 0 bank conflicts.
__global__ __launch_bounds__(512, 1) void fwd_kernel(
    const float* __restrict__ em_exp, const int* __restrict__ tags,
    const float* __restrict__ trans, const float* __restrict__ startT,
    const float* __restrict__ endT, float* __restrict__ out) {
  const int b = blockIdx.x;
  const int tid = threadIdx.x;
  const int j = tid >> 2, q = tid & 3;

  __shared__ __align__(16) float alf[2][144];          // double-buffered, padded
  __shared__ float sred[16];

  f2 eTv[16];                                          // expT rows 32q..32q+31, col j
#pragma unroll
  for (int i = 0; i < 16; ++i) {
    eTv[i].x = __expf(trans[(32 * q + 2 * i) * NUM_TAGS + j]);
    eTv[i].y = __expf(trans[(32 * q + 2 * i + 1) * NUM_TAGS + j]);
  }

  const float* embx = em_exp + (size_t)b * TT * NUM_TAGS;

  if (q == 0) alf[0][AP(j)] = __expf(startT[j]) * embx[j];

  float evA = embx[1 * NUM_TAGS + j], evB = embx[2 * NUM_TAGS + j],
        evC = embx[3 * NUM_TAGS + j], evD = embx[4 * NUM_TAGS + j];
  __syncthreads();

  int cur = 0;
  for (int t = 1; t + 3 < TT; t += 4) {                // t = 1..505, steps t..t+3
    stepv(evA, t + 0, embx, j, q, alf[cur], alf[cur ^ 1], eTv); cur ^= 1;
    stepv(evB, t + 1, embx, j, q, alf[cur], alf[cur ^ 1], eTv); cur ^= 1;
    stepv(evC, t + 2, embx, j, q, alf[cur], alf[cur ^ 1], eTv); cur ^= 1;
    stepv(evD, t + 3, embx, j, q, alf[cur], alf[cur ^ 1], eTv); cur ^= 1;
  }
  stepv(evA, 509, embx, j, q, alf[cur], alf[cur ^ 1], eTv); cur ^= 1;
  stepv(evB, 510, embx, j, q, alf[cur], alf[cur ^ 1], eTv); cur ^= 1;
  stepv(evC, 511, embx, j, q, alf[cur], alf[cur ^ 1], eTv); cur ^= 1;

  // logZ: threads 0..127 (waves 0-1), reduce alpha * exp(end)
  if (tid < 128) {
    float val = alf[cur][AP(tid)] * __expf(endT[tid]);
#pragma unroll
    for (int off = 32; off > 0; off >>= 1) val += __shfl_down(val, off, 64);
    if ((tid & 63) == 0) sred[tid >> 6] = val;
  }

  // gold: thread tid handles t = tid
  const int* tb = tags + b * TT;
  const int t = tid;
  const int tg = tb[t];
  float g = __logf(embx[t * NUM_TAGS + tg]);
  if (t < TT - 1) g += trans[tg * NUM_TAGS + tb[t + 1]];
  if (t == 0) g += startT[tb[0]] + endT[tb[TT - 1]];
#pragma unroll
  for (int off = 32; off > 0; off >>= 1) g += __shfl_down(g, off, 64);
  if ((tid & 63) == 0) sred[8 + (tid >> 6)] = g;
  __syncthreads();

  if (tid == 0) {
    float logz = __logf(sred[0] + sred[1]) + 511.0f * 7.0f * 0.69314718055994531f;
    float gs = 0.f;
#pragma unroll
    for (int i = 0; i < 8; ++i) gs += sred[8 + i];
    out[b] = logz - gs;
  }
}

extern "C" void kernel_launch(void* const* d_in, const int* in_sizes, int n_in,
                              void* d_out, int out_size, void* d_ws, size_t ws_size,
                              hipStream_t stream) {
  const int* feats = (const int*)d_in[0];
  const int* tags = (const int*)d_in[1];
  const float* sw = (const float*)d_in[2];
  const float* trans = (const float*)d_in[3];
  const float* startT = (const float*)d_in[4];
  const float* endT = (const float*)d_in[5];
  float* out = (float*)d_out;

  if (ws_size >= NEED_FULL) {
    float* swT = (float*)d_ws;
    float* em_exp = (float*)((char*)d_ws + SWT_BYTES);
    transpose_kernel<<<NUM_FEATS / 32, 256, 0, stream>>>(sw, swT);
    gather_t_kernel<<<BB * TT, 128, 0, stream>>>(feats, swT, em_exp);
    fwd_kernel<<<BB, 512, 0, stream>>>(em_exp, tags, trans, startT, endT, out);
  } else {
    float* em_exp = (float*)d_ws;
    gather_f_kernel<<<BB * TT, 128, 0, stream>>>(feats, sw, em_exp);
    fwd_kernel<<<BB, 512, 0, stream>>>(em_exp, tags, trans, startT, endT, out);
  }
}